// Round 1
// baseline (3306318.359 us; speedup 1.0000x reference)
//
#include <hip/hip_runtime.h>
#include <stdint.h>

// CharRNN MI355X — XCD-local exchange edition.
//   K1 k_prep : proj[v][h] = embedding[v,:] @ W_ih + b_h  (VOCAB=64 table)
//   K2 k_rnn  : persistent 256 blocks (1/CU). Block (gi,gj): batch rows
//               gi*32..+32, hidden cols gj*32..+32. W_hh slice bf16 in LDS.
//
//   NEW: blocks self-organize into groups by PHYSICAL XCD (s_getreg
//   HW_REG_XCC_ID + per-XCD registration). When every XCD holds exactly 32
//   blocks (the normal 1-block/CU case), the whole exchange group shares one
//   XCD L2, so:
//     - h stores  : plain write-through stores (ack at L2, not HBM —
//                   old agent-scope stores showed up as 268MB of WRITE_SIZE)
//     - h loads   : inline-asm `sc0` loads (bypass L1 only, hit dirty L2)
//     - barrier   : global_atomic_add with NO sc bits (RMW at local TCC)
//   If the 32-per-XCD check fails, fall back to the previous verified
//   agent-scope (MALL-point) path with bid-based groups — same code,
//   template<LOCAL=0>.
//
//   Deferred-wait asm loads use the rule-18 pattern: volatile load asms →
//   volatile `s_waitcnt vmcnt(0)` → sched_barrier(0) → consume.
//
// d_ws: proj f32 @0 (256KB) | cnt/reg @262144 (4KB) | ring bf16 @1MB (16MB)

#define BATCH 256
#define SEQ   512
#define HID   1024
#define VOC   64
#define EMB   256
#define FINAL_OFF (BATCH * SEQ * VOC)   // 8388608
#define RING_SLOTS 32

typedef __attribute__((ext_vector_type(8))) short short8;
typedef __attribute__((ext_vector_type(4))) float f32x4;
typedef unsigned long long u64;

__device__ inline unsigned short f2bf(float f) {
  union { float f; unsigned u; } v; v.f = f;
  unsigned u = v.u;
  return (unsigned short)((u + 0x7FFFu + ((u >> 16) & 1u)) >> 16);  // RNE
}

// ---- agent-scope (MALL-point) ops — FALLBACK path --------------------------
__device__ inline u64 cload64(const unsigned short* p) {
  return __hip_atomic_load((const u64*)p, __ATOMIC_RELAXED,
                           __HIP_MEMORY_SCOPE_AGENT);
}
__device__ inline void cstore32(unsigned short* p, unsigned v) {
  __hip_atomic_store((unsigned*)p, v, __ATOMIC_RELAXED,
                     __HIP_MEMORY_SCOPE_AGENT);
}

// ---------------- K1: projection table -------------------------------------
__global__ __launch_bounds__(256) void k_prep(const float* __restrict__ emb,
                                              const float* __restrict__ Wih,
                                              const float* __restrict__ bh,
                                              float* __restrict__ proj) {
  __shared__ float es[EMB];
  const int v = blockIdx.x >> 2;        // 0..63
  const int p = blockIdx.x & 3;         // h-quarter
  const int tid = threadIdx.x;
  es[tid] = emb[v * EMB + tid];
  __syncthreads();
  const int h = p * 256 + tid;
  float acc = bh[h];
  for (int e = 0; e < EMB; ++e) acc += es[e] * Wih[e * HID + h];
  proj[v * HID + h] = acc;
}

// ---------------- group barriers -------------------------------------------
// FALLBACK: MALL-point counter (unchanged from previous round).
__device__ inline void group_barrier(unsigned int* cnt_i, int tid, int round) {
  __syncthreads();
  if (tid == 0) {
    atomicAdd(cnt_i, 1u);
    int guard = 0;
    while (__hip_atomic_load(cnt_i, __ATOMIC_RELAXED, __HIP_MEMORY_SCOPE_AGENT)
           < 32u * (unsigned)round) {
      __builtin_amdgcn_s_sleep(1);
      if (++guard > (1 << 16)) break;    // bailout: wrong answer beats a hang
    }
  }
  __syncthreads();
}

// FAST: L2-point counter. __syncthreads' vmcnt(0) drain (stores acked at the
// XCD L2) is the release; the atomic RMW executes at the same L2; pollers
// read it with an sc0 (L1-bypass) load.
__device__ inline void group_barrier_l2(unsigned int* cnt_i, int tid,
                                        int round) {
  __syncthreads();
  if (tid == 0) {
    unsigned one = 1u;
    asm volatile("global_atomic_add %0, %1, off"
                 :: "v"(cnt_i), "v"(one) : "memory");
    int guard = 0;
    for (;;) {
      unsigned c;
      asm volatile("global_load_dword %0, %1, off sc0\n\ts_waitcnt vmcnt(0)"
                   : "=v"(c) : "v"(cnt_i) : "memory");
      if (c >= 32u * (unsigned)round) break;
      __builtin_amdgcn_s_sleep(1);
      if (++guard > (1 << 16)) break;    // bailout: wrong answer beats a hang
    }
  }
  __syncthreads();
}

// ---------------- K2 main loop (templated on coherence mode) ---------------
// LOCAL=1: exchange group is one XCD; plain stores + sc0 loads + L2 atomics.
// LOCAL=0: previous verified agent-scope path.
template <int LOCAL>
__device__ __forceinline__ void rnn_loop(
    const int* __restrict__ x, const float* __restrict__ Who,
    const float* __restrict__ bo, unsigned short* __restrict__ ring,
    float* __restrict__ out, float* __restrict__ final_out,
    unsigned int* __restrict__ cnt, const int gi, const int gj,
    unsigned short* w_lds, char* h_lds, float* p_lds, int* xs) {
  const int tid = threadIdx.x;
  const int row0 = gi * 32;
  const int lane = tid & 63, wv = tid >> 6;
  const int mt = wv & 1, nt = wv >> 1;                      // recurrence tiles
  const int l15 = lane & 15, q = lane >> 4;

  // W_ho B-fragments for this wave's 16-voc tile (compiler may rematerialize).
  short8 wf[32];
  #pragma unroll
  for (int kb = 0; kb < 32; ++kb) {
    short8 v8;
    #pragma unroll
    for (int j = 0; j < 8; ++j)
      v8[j] = (short)f2bf(Who[(kb * 32 + q * 8 + j) * VOC + wv * 16 + l15]);
    wf[kb] = v8;
  }

  unsigned int* cnt_i = cnt + gi * 32;                      // 128B-strided
  const int hcol = gj * 32 + nt * 16 + l15;
  const char* abase = h_lds + (mt * 16 + l15) * 2064 + q * 16;
  const char* bbase = (const char*)w_lds + (q * 32 + nt * 16 + l15) * 16;
  const float bias = bo[wv * 16 + l15];

  for (int t = 0; t < SEQ; ++t) {
    // 1) recurrence MFMA: 32x32 tile = h_prev(32x1024) @ Whh_slice(1024x32)
    f32x4 a0 = {0.f, 0.f, 0.f, 0.f}, a1 = {0.f, 0.f, 0.f, 0.f};
    if (t > 0) {
      #pragma unroll 4
      for (int kb = 0; kb < 32; kb += 2) {
        short8 af0 = *(const short8*)(abase + kb * 64);
        short8 bf0 = *(const short8*)(bbase + kb * 2048);
        a0 = __builtin_amdgcn_mfma_f32_16x16x32_bf16(af0, bf0, a0, 0, 0, 0);
        short8 af1 = *(const short8*)(abase + kb * 64 + 64);
        short8 bf1 = *(const short8*)(bbase + kb * 2048 + 2048);
        a1 = __builtin_amdgcn_mfma_f32_16x16x32_bf16(af1, bf1, a1, 0, 0, 0);
      }
    }
    // 2) epilogue: h_t = tanh(proj[x_t] + acc); publish packed col-pairs.
    unsigned short* slot = ring + (size_t)(t & (RING_SLOTS - 1)) * (BATCH * HID);
    float hv[4];
    #pragma unroll
    for (int r = 0; r < 4; ++r) {
      int ml = mt * 16 + q * 4 + r;                         // D row = q*4+r
      hv[r] = tanhf(p_lds[xs[ml] * 32 + nt * 16 + l15] + a0[r] + a1[r]);
      if (t == SEQ - 1) final_out[(row0 + ml) * HID + hcol] = hv[r];
    }
    #pragma unroll
    for (int r = 0; r < 4; ++r) {
      unsigned myb = f2bf(hv[r]);
      unsigned oth = (unsigned)__shfl_xor((int)myb, 1);
      if ((l15 & 1) == 0) {
        int b = row0 + mt * 16 + q * 4 + r;
        unsigned pk2 = myb | (oth << 16);
        if (LOCAL)
          *(unsigned*)(slot + (size_t)b * HID + hcol) = pk2;  // → dirty in L2
        else
          cstore32(slot + (size_t)b * HID + hcol, pk2);
      }
    }
    // 3) group barrier
    if (LOCAL) group_barrier_l2(cnt_i, tid, t + 1);
    else       group_barrier(cnt_i, tid, t + 1);
    // 4) chunked logits every 16 steps: this block does 16 rows x 1 t x 64 v
    if ((t & 15) == 15) {
      int tsel  = (t - 15) + (gj >> 1);
      int rbase = row0 + (gj & 1) * 16;
      const unsigned short* hs =
          ring + (size_t)(tsel & (RING_SLOTS - 1)) * (BATCH * HID) +
          (size_t)(rbase + l15) * HID;                      // A row base
      f32x4 lc = {0.f, 0.f, 0.f, 0.f};
      for (int g = 0; g < 4; ++g) {
        u64 hb[16];
        if (LOCAL) {
          #pragma unroll
          for (int j = 0; j < 8; ++j) {
            const unsigned short* pk = hs + (g * 8 + j) * 32 + q * 8;
            asm volatile("global_load_dwordx2 %0, %1, off sc0"
                         : "=v"(hb[2 * j]) : "v"(pk) : "memory");
            asm volatile("global_load_dwordx2 %0, %1, off offset:8 sc0"
                         : "=v"(hb[2 * j + 1]) : "v"(pk) : "memory");
          }
          asm volatile("s_waitcnt vmcnt(0)" ::: "memory");
          __builtin_amdgcn_sched_barrier(0);
        } else {
          #pragma unroll
          for (int j = 0; j < 8; ++j) {
            const unsigned short* pk = hs + (g * 8 + j) * 32 + q * 8;
            hb[2 * j]     = cload64(pk);
            hb[2 * j + 1] = cload64(pk + 4);
          }
        }
        #pragma unroll
        for (int j = 0; j < 8; ++j) {
          union { u64 d[2]; short8 s; } c;
          c.d[0] = hb[2 * j]; c.d[1] = hb[2 * j + 1];
          lc = __builtin_amdgcn_mfma_f32_16x16x32_bf16(c.s, wf[g * 8 + j],
                                                       lc, 0, 0, 0);
        }
      }
      #pragma unroll
      for (int rr = 0; rr < 4; ++rr) {
        int b = rbase + q * 4 + rr;
        out[((size_t)b * SEQ + tsel) * VOC + wv * 16 + l15] = lc[rr] + bias;
      }
      // no reuse barrier needed: 32-slot ring, reuse is >=16 barriers away
    }
    // 5) restage h_t (32 rows x 1024) -> h_lds
    if (t < SEQ - 1) {
      u64 tmp[32];
      const unsigned short* base = slot + (size_t)row0 * HID + tid * 4;
      if (LOCAL) {
        #pragma unroll
        for (int rr2 = 0; rr2 < 16; ++rr2) {
          const unsigned short* pb = base + (size_t)rr2 * 2 * HID;
          asm volatile("global_load_dwordx2 %0, %1, off sc0"
                       : "=v"(tmp[2 * rr2]) : "v"(pb) : "memory");
          asm volatile("global_load_dwordx2 %0, %1, off offset:2048 sc0"
                       : "=v"(tmp[2 * rr2 + 1]) : "v"(pb) : "memory");
        }
        asm volatile("s_waitcnt vmcnt(0)" ::: "memory");
        __builtin_amdgcn_sched_barrier(0);
      } else {
        #pragma unroll
        for (int rr = 0; rr < 32; ++rr)
          tmp[rr] = cload64(base + (size_t)rr * HID);
      }
      #pragma unroll
      for (int rr = 0; rr < 32; ++rr)
        *(u64*)(h_lds + rr * 2064 + tid * 8) = tmp[rr];
      if (tid < 32) xs[tid] = x[(row0 + tid) * SEQ + (t + 1)];
      __syncthreads();
    }
  }
}

// ---------------- K2: persistent recurrence + inline logits ----------------
// LDS: w_lds 65536 | h_lds 66048 (32 rows x 2064B) | p_lds 8192 | xs 128
__global__ __launch_bounds__(256, 1) void k_rnn(
    const int* __restrict__ x, const float* __restrict__ Whh,
    const float* __restrict__ proj, const float* __restrict__ Who,
    const float* __restrict__ bo, unsigned short* __restrict__ ring,
    float* __restrict__ out, float* __restrict__ final_out,
    unsigned int* __restrict__ cnt) {
  extern __shared__ char smem[];
  unsigned short* w_lds = (unsigned short*)smem;            // 65536
  char*           h_lds = smem + 65536;                     // 66048
  float*          p_lds = (float*)(smem + 131584);          // 8192
  int*            xs    = (int*)(smem + 139776);            // 128

  const int tid = threadIdx.x, bid = blockIdx.x;

  // --- XCD self-organization: group by physical XCD; verify 32 per XCD. ---
  // cnt[0..255]: per-group barrier counters (128B stride, 8 groups)
  // cnt[256..511]: per-XCD registration counters (128B stride)
  // cnt[512]: total-registered
  if (tid == 0) {
    unsigned xcc;
    asm volatile("s_getreg_b32 %0, hwreg(HW_REG_XCC_ID)" : "=s"(xcc));
    xcc &= 7u;
    unsigned* xreg = cnt + 256;
    unsigned* xtot = cnt + 512;
    unsigned m = atomicAdd(xreg + xcc * 32, 1u);  // returned value ⇒ completed
    atomicAdd(xtot, 1u);                          // ⇒ ordered after member add
    unsigned tot = 0; int guard = 0;
    do {
      tot = __hip_atomic_load(xtot, __ATOMIC_RELAXED, __HIP_MEMORY_SCOPE_AGENT);
      if (tot >= 256u) break;
      __builtin_amdgcn_s_sleep(2);
    } while (++guard < (1 << 16));
    int ok = (tot >= 256u) && (m < 32u);
    for (int i = 0; i < 8; ++i)
      ok &= (__hip_atomic_load(xreg + i * 32, __ATOMIC_RELAXED,
                               __HIP_MEMORY_SCOPE_AGENT) == 32u);
    xs[0] = ok;
    xs[1] = ok ? (int)xcc : (bid & 7);
    xs[2] = ok ? (int)m   : (bid >> 3);
  }
  __syncthreads();
  const int mode = xs[0];
  const int gi = xs[1], gj = xs[2];                         // group / col-slice
  __syncthreads();

  // W_hh column slice -> LDS bf16 B-fragment order (once).
  for (int it = 0; it < 128; ++it) {
    int u = it * 256 + tid;
    int n = u & 31, j8 = (u >> 5) & 7, qq = (u >> 8) & 3, kb = u >> 10;
    w_lds[((kb * 4 + qq) * 32 + n) * 8 + j8] =
        f2bf(Whh[(kb * 32 + qq * 8 + j8) * HID + gj * 32 + n]);
  }
  // proj slice [64 vocab][32 cols] -> LDS f32 (once).
  for (int it = 0; it < 8; ++it) {
    int u = it * 256 + tid;
    p_lds[u] = proj[(u >> 5) * HID + gj * 32 + (u & 31)];
  }
  if (tid < 32) xs[tid] = x[(gi * 32 + tid) * SEQ];
  __syncthreads();

  if (mode)
    rnn_loop<1>(x, Who, bo, ring, out, final_out, cnt, gi, gj,
                w_lds, h_lds, p_lds, xs);
  else
    rnn_loop<0>(x, Who, bo, ring, out, final_out, cnt, gi, gj,
                w_lds, h_lds, p_lds, xs);
}

// ---------------- launch ----------------------------------------------------
extern "C" void kernel_launch(void* const* d_in, const int* in_sizes, int n_in,
                              void* d_out, int out_size, void* d_ws, size_t ws_size,
                              hipStream_t stream) {
  const int*   x   = (const int*)d_in[0];
  const float* emb = (const float*)d_in[1];
  const float* Wih = (const float*)d_in[2];
  const float* Whh = (const float*)d_in[3];
  const float* bh  = (const float*)d_in[4];
  const float* Who = (const float*)d_in[5];
  const float* bo  = (const float*)d_in[6];
  float* out = (float*)d_out;

  char* ws = (char*)d_ws;
  float*          proj = (float*)ws;                         // 262144 B
  unsigned int*   cnt  = (unsigned int*)(ws + 262144);       // 4096 B
  unsigned short* ring = (unsigned short*)(ws + (1 << 20));  // 16 MiB

  size_t need = (size_t)(1 << 20) + (size_t)RING_SLOTS * BATCH * HID * 2;
  if (ws_size < need) return;  // diagnostic fail (absmax) instead of a fault

  (void)hipFuncSetAttribute(reinterpret_cast<const void*>(k_rnn),
                            hipFuncAttributeMaxDynamicSharedMemorySize, 139904);

  k_prep<<<256, 256, 0, stream>>>(emb, Wih, bh, proj);
  hipMemsetAsync(cnt, 0, 4096, stream);
  k_rnn<<<256, 256, 139904, stream>>>(x, Whh, proj, Who, bo, ring,
                                      out, out + FINAL_OFF, cnt);
}

// Round 2
// 2435.123 us; speedup vs baseline: 1357.7622x; 1357.7622x over previous
//
#include <hip/hip_runtime.h>
#include <stdint.h>

// CharRNN MI355X — XCD-local exchange, ATOMIC-FREE flag barrier edition.
//   K1 k_prep : proj[v][h] = embedding[v,:] @ W_ih + b_h  (VOCAB=64 table)
//   K2 k_rnn  : persistent 256 blocks (1/CU). Block (gi,gj): batch rows
//               gi*32..+32, hidden cols gj*32..+32. W_hh slice bf16 in LDS.
//
//   Round-1 post-mortem: the L2-point global_atomic_add barrier never became
//   visible to sc0 poll loads (atomic RMW evidently executes at the MALL and
//   does NOT dirty the local L2 line) -> every barrier burned its 65536-poll
//   guard -> 3.3s. The run was CORRECT, proving plain-store -> L2 -> sc0-load
//   IS coherent within an XCD. So:
//     - fast barrier: NO atomics. Per-group 32-dword flag line; member gj
//       plain-stores `round` to its slot; wave0's 32 lanes poll all slots
//       with sc0 loads until all >= round. Release = __syncthreads' vmcnt(0)
//       drain; acquire = the poll.
//     - SELF-TEST: 2 trial rounds of the flag barrier (guard 2048) right
//       after XCD registration, then a device-scope vote across 256 blocks.
//       Fast path engages only on unanimous pass; else verified agent-scope
//       fallback (2208us path). Worst-case failure cost ~0.5ms, bounded.
//
// d_ws: proj f32 @0 (256KB) | cnt arena @262144 (8KB) | ring bf16 @1MB (16MB)
// cnt dwords: 0..255 fallback barrier counters | 256..511 per-XCD reg |
//             512 reg-total | 520 vote-fail | 528 vote-total |
//             576..831 trial flags | 1024..1279 main flags

#define BATCH 256
#define SEQ   512
#define HID   1024
#define VOC   64
#define EMB   256
#define FINAL_OFF (BATCH * SEQ * VOC)   // 8388608
#define RING_SLOTS 32

typedef __attribute__((ext_vector_type(8))) short short8;
typedef __attribute__((ext_vector_type(4))) float f32x4;
typedef unsigned long long u64;

__device__ inline unsigned short f2bf(float f) {
  union { float f; unsigned u; } v; v.f = f;
  unsigned u = v.u;
  return (unsigned short)((u + 0x7FFFu + ((u >> 16) & 1u)) >> 16);  // RNE
}

// ---- agent-scope (MALL-point) ops — FALLBACK path --------------------------
__device__ inline u64 cload64(const unsigned short* p) {
  return __hip_atomic_load((const u64*)p, __ATOMIC_RELAXED,
                           __HIP_MEMORY_SCOPE_AGENT);
}
__device__ inline void cstore32(unsigned short* p, unsigned v) {
  __hip_atomic_store((unsigned*)p, v, __ATOMIC_RELAXED,
                     __HIP_MEMORY_SCOPE_AGENT);
}

// ---------------- K1: projection table -------------------------------------
__global__ __launch_bounds__(256) void k_prep(const float* __restrict__ emb,
                                              const float* __restrict__ Wih,
                                              const float* __restrict__ bh,
                                              float* __restrict__ proj) {
  __shared__ float es[EMB];
  const int v = blockIdx.x >> 2;        // 0..63
  const int p = blockIdx.x & 3;         // h-quarter
  const int tid = threadIdx.x;
  es[tid] = emb[v * EMB + tid];
  __syncthreads();
  const int h = p * 256 + tid;
  float acc = bh[h];
  for (int e = 0; e < EMB; ++e) acc += es[e] * Wih[e * HID + h];
  proj[v * HID + h] = acc;
}

// ---------------- group barriers -------------------------------------------
// FALLBACK: MALL-point counter (verified 2208us path, unchanged).
__device__ inline void group_barrier(unsigned int* cnt_i, int tid, int round) {
  __syncthreads();
  if (tid == 0) {
    atomicAdd(cnt_i, 1u);
    int guard = 0;
    while (__hip_atomic_load(cnt_i, __ATOMIC_RELAXED, __HIP_MEMORY_SCOPE_AGENT)
           < 32u * (unsigned)round) {
      __builtin_amdgcn_s_sleep(1);
      if (++guard > (1 << 16)) break;    // bailout: wrong answer beats a hang
    }
  }
  __syncthreads();
}

// FAST: atomic-free flag barrier in the XCD-local L2. Member `m` stores
// `round` to its own dword (plain store -> dirties local L2 line); wave0's
// 32 lanes poll all 32 flags with sc0 (L1-bypass) loads. Returns per-lane
// success (0 = guard timeout) — meaningful on wave0's polling lanes.
__device__ __forceinline__ int flag_barrier(unsigned* __restrict__ barg,
                                            int m, unsigned round,
                                            int guard_max) {
  __syncthreads();                       // release: vmcnt(0) drain, all waves
  int ok = 1;
  if (threadIdx.x < 64) {
    const int lane = threadIdx.x;
    if (lane == 0) {
      asm volatile("global_store_dword %0, %1, off"
                   :: "v"(barg + m), "v"(round) : "memory");
    }
    if (lane < 32) {
      unsigned v; int g = 0;
      for (;;) {
        asm volatile("global_load_dword %0, %1, off sc0\n\ts_waitcnt vmcnt(0)"
                     : "=v"(v) : "v"(barg + lane) : "memory");
        if (v >= round) break;
        __builtin_amdgcn_s_sleep(1);
        if (++g > guard_max) { ok = 0; break; }
      }
    }
  }
  __syncthreads();                       // acquire for all waves
  return ok;
}

// ---------------- K2 main loop (templated on coherence mode) ---------------
// LOCAL=1: exchange group is one XCD; plain stores + sc0 loads + flag barrier.
// LOCAL=0: previous verified agent-scope path.
template <int LOCAL>
__device__ __forceinline__ void rnn_loop(
    const int* __restrict__ x, const float* __restrict__ Who,
    const float* __restrict__ bo, unsigned short* __restrict__ ring,
    float* __restrict__ out, float* __restrict__ final_out,
    unsigned int* __restrict__ cnt, const int gi, const int gj,
    unsigned short* w_lds, char* h_lds, float* p_lds, int* xs) {
  const int tid = threadIdx.x;
  const int row0 = gi * 32;
  const int lane = tid & 63, wv = tid >> 6;
  const int mt = wv & 1, nt = wv >> 1;                      // recurrence tiles
  const int l15 = lane & 15, q = lane >> 4;

  // W_ho B-fragments for this wave's 16-voc tile (compiler may rematerialize).
  short8 wf[32];
  #pragma unroll
  for (int kb = 0; kb < 32; ++kb) {
    short8 v8;
    #pragma unroll
    for (int j = 0; j < 8; ++j)
      v8[j] = (short)f2bf(Who[(kb * 32 + q * 8 + j) * VOC + wv * 16 + l15]);
    wf[kb] = v8;
  }

  unsigned int* cnt_i = cnt + gi * 32;                      // fallback ctr
  unsigned int* barg  = cnt + 1024 + gi * 32;               // fast flag line
  const int hcol = gj * 32 + nt * 16 + l15;
  const char* abase = h_lds + (mt * 16 + l15) * 2064 + q * 16;
  const char* bbase = (const char*)w_lds + (q * 32 + nt * 16 + l15) * 16;
  const float bias = bo[wv * 16 + l15];

  for (int t = 0; t < SEQ; ++t) {
    // 1) recurrence MFMA: 32x32 tile = h_prev(32x1024) @ Whh_slice(1024x32)
    f32x4 a0 = {0.f, 0.f, 0.f, 0.f}, a1 = {0.f, 0.f, 0.f, 0.f};
    if (t > 0) {
      #pragma unroll 4
      for (int kb = 0; kb < 32; kb += 2) {
        short8 af0 = *(const short8*)(abase + kb * 64);
        short8 bf0 = *(const short8*)(bbase + kb * 2048);
        a0 = __builtin_amdgcn_mfma_f32_16x16x32_bf16(af0, bf0, a0, 0, 0, 0);
        short8 af1 = *(const short8*)(abase + kb * 64 + 64);
        short8 bf1 = *(const short8*)(bbase + kb * 2048 + 2048);
        a1 = __builtin_amdgcn_mfma_f32_16x16x32_bf16(af1, bf1, a1, 0, 0, 0);
      }
    }
    // 2) epilogue: h_t = tanh(proj[x_t] + acc); publish packed col-pairs.
    unsigned short* slot = ring + (size_t)(t & (RING_SLOTS - 1)) * (BATCH * HID);
    float hv[4];
    #pragma unroll
    for (int r = 0; r < 4; ++r) {
      int ml = mt * 16 + q * 4 + r;                         // D row = q*4+r
      hv[r] = tanhf(p_lds[xs[ml] * 32 + nt * 16 + l15] + a0[r] + a1[r]);
      if (t == SEQ - 1) final_out[(row0 + ml) * HID + hcol] = hv[r];
    }
    #pragma unroll
    for (int r = 0; r < 4; ++r) {
      unsigned myb = f2bf(hv[r]);
      unsigned oth = (unsigned)__shfl_xor((int)myb, 1);
      if ((l15 & 1) == 0) {
        int b = row0 + mt * 16 + q * 4 + r;
        unsigned pk2 = myb | (oth << 16);
        if (LOCAL)
          *(unsigned*)(slot + (size_t)b * HID + hcol) = pk2;  // → dirty in L2
        else
          cstore32(slot + (size_t)b * HID + hcol, pk2);
      }
    }
    // 3) group barrier
    if (LOCAL) flag_barrier(barg, gj, (unsigned)(t + 1), 1 << 16);
    else       group_barrier(cnt_i, tid, t + 1);
    // 4) chunked logits every 16 steps: this block does 16 rows x 1 t x 64 v
    if ((t & 15) == 15) {
      int tsel  = (t - 15) + (gj >> 1);
      int rbase = row0 + (gj & 1) * 16;
      const unsigned short* hs =
          ring + (size_t)(tsel & (RING_SLOTS - 1)) * (BATCH * HID) +
          (size_t)(rbase + l15) * HID;                      // A row base
      f32x4 lc = {0.f, 0.f, 0.f, 0.f};
      for (int g = 0; g < 4; ++g) {
        u64 hb[16];
        if (LOCAL) {
          #pragma unroll
          for (int j = 0; j < 8; ++j) {
            const unsigned short* pk = hs + (g * 8 + j) * 32 + q * 8;
            asm volatile("global_load_dwordx2 %0, %1, off sc0"
                         : "=v"(hb[2 * j]) : "v"(pk) : "memory");
            asm volatile("global_load_dwordx2 %0, %1, off offset:8 sc0"
                         : "=v"(hb[2 * j + 1]) : "v"(pk) : "memory");
          }
          asm volatile("s_waitcnt vmcnt(0)" ::: "memory");
          __builtin_amdgcn_sched_barrier(0);
        } else {
          #pragma unroll
          for (int j = 0; j < 8; ++j) {
            const unsigned short* pk = hs + (g * 8 + j) * 32 + q * 8;
            hb[2 * j]     = cload64(pk);
            hb[2 * j + 1] = cload64(pk + 4);
          }
        }
        #pragma unroll
        for (int j = 0; j < 8; ++j) {
          union { u64 d[2]; short8 s; } c;
          c.d[0] = hb[2 * j]; c.d[1] = hb[2 * j + 1];
          lc = __builtin_amdgcn_mfma_f32_16x16x32_bf16(c.s, wf[g * 8 + j],
                                                       lc, 0, 0, 0);
        }
      }
      #pragma unroll
      for (int rr = 0; rr < 4; ++rr) {
        int b = rbase + q * 4 + rr;
        out[((size_t)b * SEQ + tsel) * VOC + wv * 16 + l15] = lc[rr] + bias;
      }
      // no reuse barrier needed: 32-slot ring, reuse is >=16 barriers away
    }
    // 5) restage h_t (32 rows x 1024) -> h_lds
    if (t < SEQ - 1) {
      u64 tmp[32];
      const unsigned short* base = slot + (size_t)row0 * HID + tid * 4;
      if (LOCAL) {
        #pragma unroll
        for (int rr2 = 0; rr2 < 16; ++rr2) {
          const unsigned short* pb = base + (size_t)rr2 * 2 * HID;
          asm volatile("global_load_dwordx2 %0, %1, off sc0"
                       : "=v"(tmp[2 * rr2]) : "v"(pb) : "memory");
          asm volatile("global_load_dwordx2 %0, %1, off offset:2048 sc0"
                       : "=v"(tmp[2 * rr2 + 1]) : "v"(pb) : "memory");
        }
        asm volatile("s_waitcnt vmcnt(0)" ::: "memory");
        __builtin_amdgcn_sched_barrier(0);
      } else {
        #pragma unroll
        for (int rr = 0; rr < 32; ++rr)
          tmp[rr] = cload64(base + (size_t)rr * HID);
      }
      #pragma unroll
      for (int rr = 0; rr < 32; ++rr)
        *(u64*)(h_lds + rr * 2064 + tid * 8) = tmp[rr];
      if (tid < 32) xs[tid] = x[(row0 + tid) * SEQ + (t + 1)];
      __syncthreads();
    }
  }
}

// ---------------- K2: persistent recurrence + inline logits ----------------
// LDS: w_lds 65536 | h_lds 66048 (32 rows x 2064B) | p_lds 8192 | xs 128
__global__ __launch_bounds__(256, 1) void k_rnn(
    const int* __restrict__ x, const float* __restrict__ Whh,
    const float* __restrict__ proj, const float* __restrict__ Who,
    const float* __restrict__ bo, unsigned short* __restrict__ ring,
    float* __restrict__ out, float* __restrict__ final_out,
    unsigned int* __restrict__ cnt) {
  extern __shared__ char smem[];
  unsigned short* w_lds = (unsigned short*)smem;            // 65536
  char*           h_lds = smem + 65536;                     // 66048
  float*          p_lds = (float*)(smem + 131584);          // 8192
  int*            xs    = (int*)(smem + 139776);            // 128

  const int tid = threadIdx.x, bid = blockIdx.x;

  // --- Phase A: XCD registration (device-scope atomics at MALL) ------------
  if (tid == 0) {
    unsigned xcc;
    asm volatile("s_getreg_b32 %0, hwreg(HW_REG_XCC_ID)" : "=s"(xcc));
    xcc &= 7u;
    unsigned* xreg = cnt + 256;
    unsigned* xtot = cnt + 512;
    unsigned m = atomicAdd(xreg + xcc * 32, 1u);
    atomicAdd(xtot, 1u);
    unsigned tot = 0; int guard = 0;
    do {
      tot = __hip_atomic_load(xtot, __ATOMIC_RELAXED, __HIP_MEMORY_SCOPE_AGENT);
      if (tot >= 256u) break;
      __builtin_amdgcn_s_sleep(2);
    } while (++guard < (1 << 16));
    int ok = (tot >= 256u) && (m < 32u);
    for (int i = 0; i < 8; ++i)
      ok &= (__hip_atomic_load(xreg + i * 32, __ATOMIC_RELAXED,
                               __HIP_MEMORY_SCOPE_AGENT) == 32u);
    xs[0] = ok;                     // globally-uniform (same MALL data)
    xs[1] = (int)xcc;
    xs[2] = (int)m;
  }
  __syncthreads();
  const int regok = xs[0];
  const int gi_f  = xs[1], gj_f = xs[2];   // candidate fast-mode assignment
  __syncthreads();

  // --- Phase B: trial rounds of the fast barrier (self-test, guard 2048) ---
  int fast_ok = regok;
  if (regok) {
    unsigned* trialg = cnt + 576 + gi_f * 32;
    for (int r = 1; r <= 2; ++r) {
      int tr = flag_barrier(trialg, gj_f, (unsigned)r, 2048);
      if (tid < 64) fast_ok = fast_ok && __all(tr);
    }
  }

  // --- Phase C: unanimous vote (device-scope, MALL) ------------------------
  if (tid == 0) {
    if (!fast_ok) atomicAdd(cnt + 520, 1u);
    asm volatile("s_waitcnt vmcnt(0)" ::: "memory");  // fail-add before tot-add
    atomicAdd(cnt + 528, 1u);
    unsigned vt = 0; int guard = 0;
    do {
      vt = __hip_atomic_load(cnt + 528, __ATOMIC_RELAXED,
                             __HIP_MEMORY_SCOPE_AGENT);
      if (vt >= 256u) break;
      __builtin_amdgcn_s_sleep(2);
    } while (++guard < (1 << 16));
    unsigned vf = __hip_atomic_load(cnt + 520, __ATOMIC_RELAXED,
                                    __HIP_MEMORY_SCOPE_AGENT);
    int mode = (vt >= 256u) && (vf == 0u);
    xs[0] = mode;
    xs[1] = mode ? gi_f : (bid & 7);
    xs[2] = mode ? gj_f : (bid >> 3);
  }
  __syncthreads();
  const int mode = xs[0];
  const int gi = xs[1], gj = xs[2];                         // group / col-slice
  __syncthreads();

  // W_hh column slice -> LDS bf16 B-fragment order (once).
  for (int it = 0; it < 128; ++it) {
    int u = it * 256 + tid;
    int n = u & 31, j8 = (u >> 5) & 7, qq = (u >> 8) & 3, kb = u >> 10;
    w_lds[((kb * 4 + qq) * 32 + n) * 8 + j8] =
        f2bf(Whh[(kb * 32 + qq * 8 + j8) * HID + gj * 32 + n]);
  }
  // proj slice [64 vocab][32 cols] -> LDS f32 (once).
  for (int it = 0; it < 8; ++it) {
    int u = it * 256 + tid;
    p_lds[u] = proj[(u >> 5) * HID + gj * 32 + (u & 31)];
  }
  if (tid < 32) xs[tid] = x[(gi * 32 + tid) * SEQ];
  __syncthreads();

  if (mode)
    rnn_loop<1>(x, Who, bo, ring, out, final_out, cnt, gi, gj,
                w_lds, h_lds, p_lds, xs);
  else
    rnn_loop<0>(x, Who, bo, ring, out, final_out, cnt, gi, gj,
                w_lds, h_lds, p_lds, xs);
}

// ---------------- launch ----------------------------------------------------
extern "C" void kernel_launch(void* const* d_in, const int* in_sizes, int n_in,
                              void* d_out, int out_size, void* d_ws, size_t ws_size,
                              hipStream_t stream) {
  const int*   x   = (const int*)d_in[0];
  const float* emb = (const float*)d_in[1];
  const float* Wih = (const float*)d_in[2];
  const float* Whh = (const float*)d_in[3];
  const float* bh  = (const float*)d_in[4];
  const float* Who = (const float*)d_in[5];
  const float* bo  = (const float*)d_in[6];
  float* out = (float*)d_out;

  char* ws = (char*)d_ws;
  float*          proj = (float*)ws;                         // 262144 B
  unsigned int*   cnt  = (unsigned int*)(ws + 262144);       // 8192 B
  unsigned short* ring = (unsigned short*)(ws + (1 << 20));  // 16 MiB

  size_t need = (size_t)(1 << 20) + (size_t)RING_SLOTS * BATCH * HID * 2;
  if (ws_size < need) return;  // diagnostic fail (absmax) instead of a fault

  (void)hipFuncSetAttribute(reinterpret_cast<const void*>(k_rnn),
                            hipFuncAttributeMaxDynamicSharedMemorySize, 139904);

  k_prep<<<256, 256, 0, stream>>>(emb, Wih, bh, proj);
  hipMemsetAsync(cnt, 0, 8192, stream);
  k_rnn<<<256, 256, 139904, stream>>>(x, Whh, proj, Who, bo, ring,
                                      out, out + FINAL_OFF, cnt);
}